// Round 2
// baseline (1839.670 us; speedup 1.0000x reference)
//
#include <hip/hip_runtime.h>
#include <stdint.h>
#include <stddef.h>

// ---------------------------------------------------------------------------
// DeBERTa-v2 branch: B=8 S=512 D=768 NH=8 DH=96 L=6 SPAN=512
// bf16 MFMA compute, f32 residual/LN/softmax. Threshold 9.7e-2 budgets bf16.
// ---------------------------------------------------------------------------

typedef __bf16 bf16;
typedef __bf16 bf16x8 __attribute__((ext_vector_type(8)));
typedef float  f32x4  __attribute__((ext_vector_type(4)));

#define DEV static __device__ __forceinline__

DEV f32x4 mfma16(bf16x8 a, bf16x8 b, f32x4 c) {
  return __builtin_amdgcn_mfma_f32_16x16x32_bf16(a, b, c, 0, 0, 0);
}

// async global->LDS, 16B per lane; LDS dest = wave-uniform base + lane*16
DEV void glds16(const void* g, void* l) {
  __builtin_amdgcn_global_load_lds(
      (const __attribute__((address_space(1))) void*)g,
      (__attribute__((address_space(3))) void*)l, 16, 0, 0);
}

// ---------------------------------------------------------------------------
// Weight prep: f32 [K][N] -> bf16 [N][K] transpose (or plain convert).
// Batched: one launch handles all matrices of a layer.
// ---------------------------------------------------------------------------
struct PrepEnt { const float* src; bf16* dst; int K, N, tiles, trans; };
struct PrepArgs { PrepEnt e[10]; int n; };

__global__ __launch_bounds__(256) void prep_weights(PrepArgs a) {
  int bid = blockIdx.x, i = 0, base = 0;
  for (; i < a.n; ++i) { if (bid < base + a.e[i].tiles) break; base += a.e[i].tiles; }
  const PrepEnt E = a.e[i];
  int t = bid - base;
  int tn = E.N / 32;
  int k0 = (t / tn) * 32, n0 = (t % tn) * 32;
  int tx = threadIdx.x & 31, ty = threadIdx.x >> 5;  // 32 x 8
  if (E.trans) {
    __shared__ float tile[32][33];
#pragma unroll
    for (int q = 0; q < 4; ++q)
      tile[ty + 8 * q][tx] = E.src[(size_t)(k0 + ty + 8 * q) * E.N + n0 + tx];
    __syncthreads();
#pragma unroll
    for (int q = 0; q < 4; ++q)
      E.dst[(size_t)(n0 + ty + 8 * q) * E.K + k0 + tx] = (bf16)tile[tx][ty + 8 * q];
  } else {
#pragma unroll
    for (int q = 0; q < 4; ++q) {
      size_t off = (size_t)(k0 + ty + 8 * q) * E.N + n0 + tx;
      E.dst[off] = (bf16)E.src[off];
    }
  }
}

__global__ __launch_bounds__(256) void concat_qkv_bias(const float* bq, const float* bk,
                                                       const float* bv, float* dst) {
  int l = blockIdx.y;
  int i = blockIdx.x * 256 + threadIdx.x;  // 9*256 = 2304 exact
  float v = (i < 768) ? bq[l * 768 + i] : (i < 1536) ? bk[l * 768 + i - 768]
                                                     : bv[l * 768 + i - 1536];
  dst[l * 2304 + i] = v;
}
__global__ __launch_bounds__(256) void concat_pp_bias(const float* bpk, const float* bpq,
                                                      float* dst) {
  int l = blockIdx.y;
  int i = blockIdx.x * 256 + threadIdx.x;  // 6*256 = 1536 exact
  float v = (i < 768) ? bpk[l * 768 + i] : bpq[l * 768 + i - 768];
  dst[l * 1536 + i] = v;
}

// ---------------------------------------------------------------------------
// GEMM: C[M,N] = A[M,K](bf16,row) @ Bt[N,K](bf16,row)^T + bias
// m97 structure: BK=32, 4 waves (2x2), global_load_lds w16, 2-phase dbuf.
// EPI: 0 = bf16 out; 1 = exact GELU -> bf16 out; 2 = f32 out (pre-LN)
// ---------------------------------------------------------------------------
template <int BM, int BN, int EPI>
__global__ __launch_bounds__(256) void gemm_bt(const bf16* __restrict__ A,
                                               const bf16* __restrict__ Bt,
                                               const float* __restrict__ bias,
                                               bf16* __restrict__ Cb, float* __restrict__ Cf,
                                               int M, int N, int K) {
  __shared__ __align__(16) bf16 As[2][BM * 32];
  __shared__ __align__(16) bf16 Bs[2][BN * 32];
  const int tid = threadIdx.x;
  const int wid = tid >> 6, lane = tid & 63;
  const int lr = lane & 15, lg = lane >> 4;
  const int m0 = blockIdx.y * BM, n0 = blockIdx.x * BN;
  constexpr int WM = BM / 2, WN = BN / 2, MI = WM / 16, NI = WN / 16;
  constexpr int IA = BM / 64, IB = BN / 64;
  const int wr = (wid & 1) * WM, wc = (wid >> 1) * WN;

  f32x4 acc[MI][NI];
#pragma unroll
  for (int i = 0; i < MI; ++i)
#pragma unroll
    for (int j = 0; j < NI; ++j) acc[i][j] = f32x4{0.f, 0.f, 0.f, 0.f};

  auto stage = [&](int buf, int kt) {
    const int k0 = kt * 32;
#pragma unroll
    for (int p = 0; p < IA; ++p) {
      int idx = (wid * IA + p) * 64 + lane;
      int r = idx >> 2, c = (idx & 3) * 8;
      glds16(A + (size_t)(m0 + r) * K + k0 + c, (char*)(&As[buf][0]) + (wid * IA + p) * 1024);
    }
#pragma unroll
    for (int p = 0; p < IB; ++p) {
      int idx = (wid * IB + p) * 64 + lane;
      int r = idx >> 2, c = (idx & 3) * 8;
      glds16(Bt + (size_t)(n0 + r) * K + k0 + c, (char*)(&Bs[buf][0]) + (wid * IB + p) * 1024);
    }
  };

  stage(0, 0);
  __syncthreads();
  const int nt = K >> 5;
  int cur = 0;
  for (int kt = 0; kt < nt; ++kt) {
    if (kt + 1 < nt) stage(cur ^ 1, kt + 1);
    bf16x8 af[MI], bv[NI];
#pragma unroll
    for (int mi = 0; mi < MI; ++mi)
      af[mi] = *(const bf16x8*)(&As[cur][(wr + mi * 16 + lr) * 32 + lg * 8]);
#pragma unroll
    for (int ni = 0; ni < NI; ++ni)
      bv[ni] = *(const bf16x8*)(&Bs[cur][(wc + ni * 16 + lr) * 32 + lg * 8]);
#pragma unroll
    for (int mi = 0; mi < MI; ++mi)
#pragma unroll
      for (int ni = 0; ni < NI; ++ni) acc[mi][ni] = mfma16(af[mi], bv[ni], acc[mi][ni]);
    __syncthreads();
    cur ^= 1;
  }

#pragma unroll
  for (int ni = 0; ni < NI; ++ni) {
    const int col = n0 + wc + ni * 16 + lr;
    const float bvv = bias[col];
#pragma unroll
    for (int mi = 0; mi < MI; ++mi) {
#pragma unroll
      for (int r = 0; r < 4; ++r) {
        const int row = m0 + wr + mi * 16 + lg * 4 + r;
        float v = acc[mi][ni][r] + bvv;
        if constexpr (EPI == 1) v = 0.5f * v * (1.f + erff(v * 0.70710678118654752f));
        if constexpr (EPI == 2) Cf[(size_t)row * N + col] = v;
        else Cb[(size_t)row * N + col] = (bf16)v;
      }
    }
  }
}

// ---------------------------------------------------------------------------
// LayerNorm kernels (f32), one row (768) per 256-thread block.
// ---------------------------------------------------------------------------
__global__ __launch_bounds__(256) void ln_res_kernel(const float* __restrict__ xin,
                                                     const float* __restrict__ res,
                                                     const float* __restrict__ gw,
                                                     const float* __restrict__ bw,
                                                     float* __restrict__ o32,
                                                     bf16* __restrict__ ob) {
  const int row = blockIdx.x, t = threadIdx.x;
  const size_t base = (size_t)row * 768;
  float v[3];
  float s = 0.f, s2 = 0.f;
#pragma unroll
  for (int k = 0; k < 3; ++k) {
    int c = t + k * 256;
    v[k] = xin[base + c] + res[base + c];
    s += v[k]; s2 += v[k] * v[k];
  }
#pragma unroll
  for (int m = 1; m < 64; m <<= 1) { s += __shfl_xor(s, m, 64); s2 += __shfl_xor(s2, m, 64); }
  __shared__ float ws[4], ws2[4];
  if ((t & 63) == 0) { ws[t >> 6] = s; ws2[t >> 6] = s2; }
  __syncthreads();
  s = ws[0] + ws[1] + ws[2] + ws[3];
  s2 = ws2[0] + ws2[1] + ws2[2] + ws2[3];
  const float mean = s * (1.f / 768.f);
  const float var = s2 * (1.f / 768.f) - mean * mean;
  const float rstd = rsqrtf(var + 1e-7f);
#pragma unroll
  for (int k = 0; k < 3; ++k) {
    int c = t + k * 256;
    float y = (v[k] - mean) * rstd * gw[c] + bw[c];
    o32[base + c] = y;
    ob[base + c] = (bf16)y;
  }
}

__global__ __launch_bounds__(256) void ln_emb_kernel(const float* __restrict__ x,
                                                     const float* __restrict__ pos,
                                                     const float* __restrict__ gw,
                                                     const float* __restrict__ bw,
                                                     const int* __restrict__ mask,
                                                     float* __restrict__ o32,
                                                     bf16* __restrict__ ob) {
  const int row = blockIdx.x, t = threadIdx.x;
  const int sp = row & 511;
  const size_t base = (size_t)row * 768;
  float v[3];
  float s = 0.f, s2 = 0.f;
#pragma unroll
  for (int k = 0; k < 3; ++k) {
    int c = t + k * 256;
    v[k] = x[base + c] + pos[(size_t)sp * 768 + c];
    s += v[k]; s2 += v[k] * v[k];
  }
#pragma unroll
  for (int m = 1; m < 64; m <<= 1) { s += __shfl_xor(s, m, 64); s2 += __shfl_xor(s2, m, 64); }
  __shared__ float ws[4], ws2[4];
  if ((t & 63) == 0) { ws[t >> 6] = s; ws2[t >> 6] = s2; }
  __syncthreads();
  s = ws[0] + ws[1] + ws[2] + ws[3];
  s2 = ws2[0] + ws2[1] + ws2[2] + ws2[3];
  const float mean = s * (1.f / 768.f);
  const float var = s2 * (1.f / 768.f) - mean * mean;
  const float rstd = rsqrtf(var + 1e-7f);
  const float mk = (float)mask[row];
#pragma unroll
  for (int k = 0; k < 3; ++k) {
    int c = t + k * 256;
    float y = ((v[k] - mean) * rstd * gw[c] + bw[c]) * mk;
    o32[base + c] = y;
    ob[base + c] = (bf16)y;
  }
}

// ---------------------------------------------------------------------------
// Fused disentangled attention. Grid (8 q-tiles, NH, B), 256 threads (4 waves).
// scores[i,j] = (q_i.k_j + q_i.pk[i-j+512] + k_j.pq[i-j+512]) / sqrt(288)
// Band rows d = i-j+512 ∈ [d0, d0+126], d0 = i0-j0+449 (never <0; clamp 1023).
// Flash softmax over 8 k-tiles of 64. LDS tiles [rows][96]: 192B stride is
// conflict-free for the b128 fragment pattern (full-wave bank accounting).
// ---------------------------------------------------------------------------
__global__ __launch_bounds__(256) void attn_kernel(const bf16* __restrict__ qkv,
                                                   const bf16* __restrict__ pkpq,
                                                   const int* __restrict__ mask,
                                                   bf16* __restrict__ ctx) {
  constexpr float INV_SCALE = 0.05892556509887897f;  // 1/sqrt(288)
  constexpr float NEG = -3.402823466e38f;
  const int qt = blockIdx.x, h = blockIdx.y, b = blockIdx.z;
  const int i0 = qt * 64;
  const int tid = threadIdx.x;
  const int wid = tid >> 6, lane = tid & 63;
  const int lr = lane & 15, lg = lane >> 4;
  const int w16 = wid * 16;

  __shared__ __align__(16) bf16 Qs[64 * 96];
  __shared__ __align__(16) bf16 Ks[64 * 96];
  __shared__ __align__(16) bf16 PKs[128 * 96];
  __shared__ __align__(16) bf16 PQs[128 * 96];
  __shared__ __align__(16) bf16 Vst[96 * 80];   // V transposed, 80-pad rows
  __shared__ __align__(16) bf16 G1s[64 * 128];  // q . pk band
  __shared__ __align__(16) bf16 G2s[64 * 128];  // k . pq band
  __shared__ __align__(16) bf16 Ps[64 * 64];    // softmax probs

  // stage Q once (12 x 1KB wave-issues)
#pragma unroll
  for (int p = 0; p < 3; ++p) {
    int idx = (wid * 3 + p) * 64 + lane;
    int r = idx / 12, c = idx % 12;
    glds16(qkv + (size_t)(b * 512 + i0 + r) * 2304 + h * 96 + c * 8,
           (char*)Qs + (wid * 3 + p) * 1024);
  }

  int qm[4];
#pragma unroll
  for (int r = 0; r < 4; ++r) qm[r] = mask[b * 512 + i0 + w16 + lg * 4 + r];

  f32x4 O[6];
#pragma unroll
  for (int dt = 0; dt < 6; ++dt) O[dt] = f32x4{0.f, 0.f, 0.f, 0.f};
  float mrun[4] = {NEG, NEG, NEG, NEG};
  float lrun[4] = {0.f, 0.f, 0.f, 0.f};

  for (int jt = 0; jt < 8; ++jt) {
    const int j0 = jt * 64;
    const int d0 = i0 - j0 + 449;
    __syncthreads();  // prior-iter LDS reads done; also drains Q stage on jt=0
    // stage K
#pragma unroll
    for (int p = 0; p < 3; ++p) {
      int idx = (wid * 3 + p) * 64 + lane;
      int r = idx / 12, c = idx % 12;
      glds16(qkv + (size_t)(b * 512 + j0 + r) * 2304 + 768 + h * 96 + c * 8,
             (char*)Ks + (wid * 3 + p) * 1024);
    }
    // stage PK/PQ band (128 rows, last row unused if clamped)
#pragma unroll
    for (int p = 0; p < 6; ++p) {
      int idx = (wid * 6 + p) * 64 + lane;
      int r = idx / 12, c = idx % 12;
      int gr = d0 + r; gr = gr > 1023 ? 1023 : gr;
      glds16(pkpq + (size_t)gr * 1536 + h * 96 + c * 8, (char*)PKs + (wid * 6 + p) * 1024);
      glds16(pkpq + (size_t)gr * 1536 + 768 + h * 96 + c * 8, (char*)PQs + (wid * 6 + p) * 1024);
    }
    // stage V transposed (reg path; conflict-free writes: lanes = consecutive j)
    {
      int j = tid & 63;
      int dcb = (tid >> 6) * 3;
#pragma unroll
      for (int q = 0; q < 3; ++q) {
        bf16x8 vv = *(const bf16x8*)(qkv + (size_t)(b * 512 + j0 + j) * 2304 + 1536 + h * 96 +
                                     (dcb + q) * 8);
#pragma unroll
        for (int e = 0; e < 8; ++e) Vst[((dcb + q) * 8 + e) * 80 + j] = vv[e];
      }
    }
    __syncthreads();

    f32x4 g[8];
    // G1 = Qtile @ PK^T  [64 x 128]
#pragma unroll
    for (int dt = 0; dt < 8; ++dt) g[dt] = f32x4{0.f, 0.f, 0.f, 0.f};
#pragma unroll
    for (int ks = 0; ks < 3; ++ks) {
      bf16x8 a = *(const bf16x8*)(&Qs[(w16 + lr) * 96 + ks * 32 + lg * 8]);
#pragma unroll
      for (int dt = 0; dt < 8; ++dt) {
        bf16x8 bb = *(const bf16x8*)(&PKs[(dt * 16 + lr) * 96 + ks * 32 + lg * 8]);
        g[dt] = mfma16(a, bb, g[dt]);
      }
    }
#pragma unroll
    for (int dt = 0; dt < 8; ++dt)
#pragma unroll
      for (int r = 0; r < 4; ++r)
        G1s[(w16 + lg * 4 + r) * 128 + dt * 16 + lr] = (bf16)g[dt][r];

    // G2 = Ktile @ PQ^T  [64 x 128]
#pragma unroll
    for (int dt = 0; dt < 8; ++dt) g[dt] = f32x4{0.f, 0.f, 0.f, 0.f};
#pragma unroll
    for (int ks = 0; ks < 3; ++ks) {
      bf16x8 a = *(const bf16x8*)(&Ks[(w16 + lr) * 96 + ks * 32 + lg * 8]);
#pragma unroll
      for (int dt = 0; dt < 8; ++dt) {
        bf16x8 bb = *(const bf16x8*)(&PQs[(dt * 16 + lr) * 96 + ks * 32 + lg * 8]);
        g[dt] = mfma16(a, bb, g[dt]);
      }
    }
#pragma unroll
    for (int dt = 0; dt < 8; ++dt)
#pragma unroll
      for (int r = 0; r < 4; ++r)
        G2s[(w16 + lg * 4 + r) * 128 + dt * 16 + lr] = (bf16)g[dt][r];

    // QK^T [64 x 64]
    f32x4 sv[4];
#pragma unroll
    for (int n = 0; n < 4; ++n) sv[n] = f32x4{0.f, 0.f, 0.f, 0.f};
#pragma unroll
    for (int ks = 0; ks < 3; ++ks) {
      bf16x8 a = *(const bf16x8*)(&Qs[(w16 + lr) * 96 + ks * 32 + lg * 8]);
#pragma unroll
      for (int n = 0; n < 4; ++n) {
        bf16x8 bb = *(const bf16x8*)(&Ks[(n * 16 + lr) * 96 + ks * 32 + lg * 8]);
        sv[n] = mfma16(a, bb, sv[n]);
      }
    }
    __syncthreads();  // G1s/G2s visible across waves

    int km[4];
#pragma unroll
    for (int n = 0; n < 4; ++n) km[n] = mask[b * 512 + j0 + n * 16 + lr];

    // assemble scores: gather band terms  (dd = li - lj + 63 ∈ [0,126])
    float pv[4][4];
#pragma unroll
    for (int n = 0; n < 4; ++n) {
      const int lj = n * 16 + lr;
#pragma unroll
      for (int r = 0; r < 4; ++r) {
        const int li = w16 + lg * 4 + r;
        const int dd = li - lj + 63;
        float t = (sv[n][r] + (float)G1s[li * 128 + dd] + (float)G2s[lj * 128 + dd]) * INV_SCALE;
        pv[n][r] = (qm[r] != 0 && km[n] != 0) ? t : NEG;
      }
    }

    // flash-softmax update (rows live in 16-lane groups)
    float alpha[4];
#pragma unroll
    for (int r = 0; r < 4; ++r) {
      float mx = fmaxf(fmaxf(pv[0][r], pv[1][r]), fmaxf(pv[2][r], pv[3][r]));
#pragma unroll
      for (int m = 1; m < 16; m <<= 1) mx = fmaxf(mx, __shfl_xor(mx, m, 64));
      float mn = fmaxf(mrun[r], mx);
      alpha[r] = __expf(mrun[r] - mn);
      mrun[r] = mn;
    }
#pragma unroll
    for (int n = 0; n < 4; ++n)
#pragma unroll
      for (int r = 0; r < 4; ++r) pv[n][r] = __expf(pv[n][r] - mrun[r]);
#pragma unroll
    for (int r = 0; r < 4; ++r) {
      float sm = pv[0][r] + pv[1][r] + pv[2][r] + pv[3][r];
#pragma unroll
      for (int m = 1; m < 16; m <<= 1) sm += __shfl_xor(sm, m, 64);
      lrun[r] = lrun[r] * alpha[r] + sm;
    }
#pragma unroll
    for (int n = 0; n < 4; ++n)
#pragma unroll
      for (int r = 0; r < 4; ++r)
        Ps[(w16 + lg * 4 + r) * 64 + n * 16 + lr] = (bf16)pv[n][r];
#pragma unroll
    for (int dt = 0; dt < 6; ++dt)
#pragma unroll
      for (int r = 0; r < 4; ++r) O[dt][r] *= alpha[r];
    // PV (same-wave Ps rows; LDS pipe is in-order per wave)
#pragma unroll
    for (int js = 0; js < 2; ++js) {
      bf16x8 a = *(const bf16x8*)(&Ps[(w16 + lr) * 64 + js * 32 + lg * 8]);
#pragma unroll
      for (int dt = 0; dt < 6; ++dt) {
        bf16x8 bb = *(const bf16x8*)(&Vst[(dt * 16 + lr) * 80 + js * 32 + lg * 8]);
        O[dt] = mfma16(a, bb, O[dt]);
      }
    }
  }

  float inv[4];
#pragma unroll
  for (int r = 0; r < 4; ++r) inv[r] = 1.f / lrun[r];
#pragma unroll
  for (int dt = 0; dt < 6; ++dt)
#pragma unroll
    for (int r = 0; r < 4; ++r)
      ctx[(size_t)(b * 512 + i0 + w16 + lg * 4 + r) * 768 + h * 96 + dt * 16 + lr] =
          (bf16)(O[dt][r] * inv[r]);
}

// ---------------------------------------------------------------------------
// Host orchestration
// ---------------------------------------------------------------------------
extern "C" void kernel_launch(void* const* d_in, const int* in_sizes, int n_in, void* d_out,
                              int out_size, void* d_ws, size_t ws_size, hipStream_t stream) {
  const float* x    = (const float*)d_in[0];
  const float* pos  = (const float*)d_in[1];
  const float* rel  = (const float*)d_in[2];
  const float* lneg = (const float*)d_in[3];
  const float* lneb = (const float*)d_in[4];
  const float* Wq   = (const float*)d_in[5];
  const float* bq   = (const float*)d_in[6];
  const float* Wk   = (const float*)d_in[7];
  const float* bk   = (const float*)d_in[8];
  const float* Wv   = (const float*)d_in[9];
  const float* bv   = (const float*)d_in[10];
  const float* Wo   = (const float*)d_in[11];
  const float* bo   = (const float*)d_in[12];
  const float* Wpk  = (const float*)d_in[13];
  const float* bpk  = (const float*)d_in[14];
  const float* Wpq  = (const float*)d_in[15];
  const float* bpq  = (const float*)d_in[16];
  const float* ln1g = (const float*)d_in[17];
  const float* ln1b = (const float*)d_in[18];
  const float* Wi   = (const float*)d_in[19];
  const float* bi   = (const float*)d_in[20];
  const float* Wo2  = (const float*)d_in[21];
  const float* bo2  = (const float*)d_in[22];
  const float* ln2g = (const float*)d_in[23];
  const float* ln2b = (const float*)d_in[24];
  const int* mask   = (const int*)d_in[25];
  float* out = (float*)d_out;

  char* w = (char*)d_ws;
  auto alloc = [&](size_t bytes) { char* p = w; w += (bytes + 255) & ~(size_t)255; return p; };
  bf16* wqkvT = (bf16*)alloc((size_t)2304 * 768 * 2);
  bf16* woT   = (bf16*)alloc((size_t)768 * 768 * 2);
  bf16* wppT  = (bf16*)alloc((size_t)1536 * 768 * 2);
  bf16* wiT   = (bf16*)alloc((size_t)3072 * 768 * 2);
  bf16* wo2T  = (bf16*)alloc((size_t)768 * 3072 * 2);
  bf16* relb  = (bf16*)alloc((size_t)1024 * 768 * 2);
  float* h32  = (float*)alloc((size_t)4096 * 768 * 4);
  bf16* hb    = (bf16*)alloc((size_t)4096 * 768 * 2);
  bf16* qkvb  = (bf16*)alloc((size_t)4096 * 2304 * 2);
  bf16* ppb   = (bf16*)alloc((size_t)1024 * 1536 * 2);
  bf16* ctxb  = (bf16*)alloc((size_t)4096 * 768 * 2);
  float* t32  = (float*)alloc((size_t)4096 * 768 * 4);
  bf16* ffib  = (bf16*)alloc((size_t)4096 * 3072 * 2);
  float* bqkvF = (float*)alloc((size_t)6 * 2304 * 4);
  float* bppF  = (float*)alloc((size_t)6 * 1536 * 4);
  (void)ws_size; (void)in_sizes; (void)n_in; (void)out_size;

  // embeddings LN (+mask)
  ln_emb_kernel<<<4096, 256, 0, stream>>>(x, pos, lneg, lneb, mask, h32, hb);
  // all-layer bias concats
  concat_qkv_bias<<<dim3(9, 6), 256, 0, stream>>>(bq, bk, bv, bqkvF);
  concat_pp_bias<<<dim3(6, 6), 256, 0, stream>>>(bpk, bpq, bppF);

  for (int l = 0; l < 6; ++l) {
    PrepArgs pa;
    int n = 0, total = 0;
    auto add = [&](const float* s, bf16* d, int Kd, int Nd, int tr) {
      pa.e[n].src = s; pa.e[n].dst = d; pa.e[n].K = Kd; pa.e[n].N = Nd;
      pa.e[n].tiles = (Kd / 32) * (Nd / 32); pa.e[n].trans = tr;
      total += pa.e[n].tiles; ++n;
    };
    add(Wq + (size_t)l * 768 * 768, wqkvT, 768, 768, 1);
    add(Wk + (size_t)l * 768 * 768, wqkvT + (size_t)768 * 768, 768, 768, 1);
    add(Wv + (size_t)l * 768 * 768, wqkvT + (size_t)1536 * 768, 768, 768, 1);
    add(Wo + (size_t)l * 768 * 768, woT, 768, 768, 1);
    add(Wpk + (size_t)l * 768 * 768, wppT, 768, 768, 1);
    add(Wpq + (size_t)l * 768 * 768, wppT + (size_t)768 * 768, 768, 768, 1);
    add(Wi + (size_t)l * 768 * 3072, wiT, 768, 3072, 1);
    add(Wo2 + (size_t)l * 3072 * 768, wo2T, 3072, 768, 1);
    if (l == 0) add(rel, relb, 1024, 768, 0);
    pa.n = n;
    prep_weights<<<total, 256, 0, stream>>>(pa);

    // QKV: [4096,768] @ [768,2304]
    gemm_bt<128, 128, 0><<<dim3(2304 / 128, 4096 / 128), 256, 0, stream>>>(
        hb, wqkvT, bqkvF + l * 2304, qkvb, nullptr, 4096, 2304, 768);
    // pk|pq: [1024,768] @ [768,1536]
    gemm_bt<128, 128, 0><<<dim3(1536 / 128, 1024 / 128), 256, 0, stream>>>(
        relb, wppT, bppF + l * 1536, ppb, nullptr, 1024, 1536, 768);
    // attention
    attn_kernel<<<dim3(8, 8, 8), 256, 0, stream>>>(qkvb, ppb, mask, ctxb);
    // out-proj -> f32
    gemm_bt<64, 128, 2><<<dim3(768 / 128, 4096 / 64), 256, 0, stream>>>(
        ctxb, woT, bo + (size_t)l * 768, nullptr, t32, 4096, 768, 768);
    ln_res_kernel<<<4096, 256, 0, stream>>>(t32, h32, ln1g + l * 768, ln1b + l * 768, h32, hb);
    // FFN1 + exact GELU
    gemm_bt<128, 128, 1><<<dim3(3072 / 128, 4096 / 128), 256, 0, stream>>>(
        hb, wiT, bi + (size_t)l * 3072, ffib, nullptr, 4096, 3072, 768);
    // FFN2 -> f32
    gemm_bt<64, 128, 2><<<dim3(768 / 128, 4096 / 64), 256, 0, stream>>>(
        ffib, wo2T, bo2 + (size_t)l * 768, nullptr, t32, 4096, 768, 3072);
    float* oo = (l == 5) ? out : h32;
    ln_res_kernel<<<4096, 256, 0, stream>>>(t32, h32, ln2g + l * 768, ln2b + l * 768, oo, hb);
  }
}

// Round 3
// 1734.614 us; speedup vs baseline: 1.0606x; 1.0606x over previous
//
#include <hip/hip_runtime.h>
#include <stdint.h>
#include <stddef.h>

// ---------------------------------------------------------------------------
// DeBERTa-v2 branch: B=8 S=512 D=768 NH=8 DH=96 L=6 SPAN=512
// bf16 MFMA compute, f32 residual/LN/softmax.
// ---------------------------------------------------------------------------

typedef __bf16 bf16;
typedef __bf16 bf16x4 __attribute__((ext_vector_type(4)));
typedef __bf16 bf16x8 __attribute__((ext_vector_type(8)));
typedef float  f32x4  __attribute__((ext_vector_type(4)));

#define DEV static __device__ __forceinline__

DEV f32x4 mfma16(bf16x8 a, bf16x8 b, f32x4 c) {
  return __builtin_amdgcn_mfma_f32_16x16x32_bf16(a, b, c, 0, 0, 0);
}

// async global->LDS, 16B/lane; LDS dest = wave-uniform base + lane*16
DEV void glds16(const void* g, void* l) {
  __builtin_amdgcn_global_load_lds(
      (const __attribute__((address_space(1))) void*)g,
      (__attribute__((address_space(3))) void*)l, 16, 0, 0);
}

// ---------------------------------------------------------------------------
// Weight prep: f32 [K][N] -> bf16 [N][K] transpose (or plain convert).
// ---------------------------------------------------------------------------
struct PrepEnt { const float* src; bf16* dst; int K, N, tiles, trans; };
struct PrepArgs { PrepEnt e[10]; int n; };

__global__ __launch_bounds__(256) void prep_weights(PrepArgs a) {
  int bid = blockIdx.x, i = 0, base = 0;
  for (; i < a.n; ++i) { if (bid < base + a.e[i].tiles) break; base += a.e[i].tiles; }
  const PrepEnt E = a.e[i];
  int t = bid - base;
  int tn = E.N / 32;
  int k0 = (t / tn) * 32, n0 = (t % tn) * 32;
  int tx = threadIdx.x & 31, ty = threadIdx.x >> 5;  // 32 x 8
  if (E.trans) {
    __shared__ float tile[32][33];
#pragma unroll
    for (int q = 0; q < 4; ++q)
      tile[ty + 8 * q][tx] = E.src[(size_t)(k0 + ty + 8 * q) * E.N + n0 + tx];
    __syncthreads();
#pragma unroll
    for (int q = 0; q < 4; ++q)
      E.dst[(size_t)(n0 + ty + 8 * q) * E.K + k0 + tx] = (bf16)tile[tx][ty + 8 * q];
  } else {
#pragma unroll
    for (int q = 0; q < 4; ++q) {
      size_t off = (size_t)(k0 + ty + 8 * q) * E.N + n0 + tx;
      E.dst[off] = (bf16)E.src[off];
    }
  }
}

__global__ __launch_bounds__(256) void concat_qkv_bias(const float* bq, const float* bk,
                                                       const float* bv, float* dst) {
  int l = blockIdx.y;
  int i = blockIdx.x * 256 + threadIdx.x;
  float v = (i < 768) ? bq[l * 768 + i] : (i < 1536) ? bk[l * 768 + i - 768]
                                                     : bv[l * 768 + i - 1536];
  dst[l * 2304 + i] = v;
}
__global__ __launch_bounds__(256) void concat_pp_bias(const float* bpk, const float* bpq,
                                                      float* dst) {
  int l = blockIdx.y;
  int i = blockIdx.x * 256 + threadIdx.x;
  float v = (i < 768) ? bpk[l * 768 + i] : bpq[l * 768 + i - 768];
  dst[l * 1536 + i] = v;
}

// ---------------------------------------------------------------------------
// GEMM (m97 structure, unchanged from R2 — known-good).
// ---------------------------------------------------------------------------
template <int BM, int BN, int EPI>
__global__ __launch_bounds__(256) void gemm_bt(const bf16* __restrict__ A,
                                               const bf16* __restrict__ Bt,
                                               const float* __restrict__ bias,
                                               bf16* __restrict__ Cb, float* __restrict__ Cf,
                                               int M, int N, int K) {
  __shared__ __align__(16) bf16 As[2][BM * 32];
  __shared__ __align__(16) bf16 Bs[2][BN * 32];
  const int tid = threadIdx.x;
  const int wid = tid >> 6, lane = tid & 63;
  const int lr = lane & 15, lg = lane >> 4;
  const int m0 = blockIdx.y * BM, n0 = blockIdx.x * BN;
  constexpr int WM = BM / 2, WN = BN / 2, MI = WM / 16, NI = WN / 16;
  constexpr int IA = BM / 64, IB = BN / 64;
  const int wr = (wid & 1) * WM, wc = (wid >> 1) * WN;

  f32x4 acc[MI][NI];
#pragma unroll
  for (int i = 0; i < MI; ++i)
#pragma unroll
    for (int j = 0; j < NI; ++j) acc[i][j] = f32x4{0.f, 0.f, 0.f, 0.f};

  auto stage = [&](int buf, int kt) {
    const int k0 = kt * 32;
#pragma unroll
    for (int p = 0; p < IA; ++p) {
      int idx = (wid * IA + p) * 64 + lane;
      int r = idx >> 2, c = (idx & 3) * 8;
      glds16(A + (size_t)(m0 + r) * K + k0 + c, (char*)(&As[buf][0]) + (wid * IA + p) * 1024);
    }
#pragma unroll
    for (int p = 0; p < IB; ++p) {
      int idx = (wid * IB + p) * 64 + lane;
      int r = idx >> 2, c = (idx & 3) * 8;
      glds16(Bt + (size_t)(n0 + r) * K + k0 + c, (char*)(&Bs[buf][0]) + (wid * IB + p) * 1024);
    }
  };

  stage(0, 0);
  __syncthreads();
  const int nt = K >> 5;
  int cur = 0;
  for (int kt = 0; kt < nt; ++kt) {
    if (kt + 1 < nt) stage(cur ^ 1, kt + 1);
    bf16x8 af[MI], bv[NI];
#pragma unroll
    for (int mi = 0; mi < MI; ++mi)
      af[mi] = *(const bf16x8*)(&As[cur][(wr + mi * 16 + lr) * 32 + lg * 8]);
#pragma unroll
    for (int ni = 0; ni < NI; ++ni)
      bv[ni] = *(const bf16x8*)(&Bs[cur][(wc + ni * 16 + lr) * 32 + lg * 8]);
#pragma unroll
    for (int mi = 0; mi < MI; ++mi)
#pragma unroll
      for (int ni = 0; ni < NI; ++ni) acc[mi][ni] = mfma16(af[mi], bv[ni], acc[mi][ni]);
    __syncthreads();
    cur ^= 1;
  }

#pragma unroll
  for (int ni = 0; ni < NI; ++ni) {
    const int col = n0 + wc + ni * 16 + lr;
    const float bvv = bias[col];
#pragma unroll
    for (int mi = 0; mi < MI; ++mi) {
#pragma unroll
      for (int r = 0; r < 4; ++r) {
        const int row = m0 + wr + mi * 16 + lg * 4 + r;
        float v = acc[mi][ni][r] + bvv;
        if constexpr (EPI == 1) v = 0.5f * v * (1.f + erff(v * 0.70710678118654752f));
        if constexpr (EPI == 2) Cf[(size_t)row * N + col] = v;
        else Cb[(size_t)row * N + col] = (bf16)v;
      }
    }
  }
}

// ---------------------------------------------------------------------------
// LayerNorm: one 64-lane wave per row (768), float4 vector loads (G13).
// ---------------------------------------------------------------------------
__global__ __launch_bounds__(64) void ln_res_kernel(const float* __restrict__ xin,
                                                    const float* __restrict__ res,
                                                    const float* __restrict__ gw,
                                                    const float* __restrict__ bw,
                                                    float* __restrict__ o32,
                                                    bf16* __restrict__ ob) {
  const int row = blockIdx.x, t = threadIdx.x;
  const size_t base = (size_t)row * 768;
  const float4* xv = (const float4*)(xin + base);
  const float4* rv = (const float4*)(res + base);
  float4 v[3];
  float s = 0.f, s2 = 0.f;
#pragma unroll
  for (int k = 0; k < 3; ++k) {
    float4 a = xv[t + k * 64], b = rv[t + k * 64];
    v[k] = make_float4(a.x + b.x, a.y + b.y, a.z + b.z, a.w + b.w);
    s += v[k].x + v[k].y + v[k].z + v[k].w;
    s2 += v[k].x * v[k].x + v[k].y * v[k].y + v[k].z * v[k].z + v[k].w * v[k].w;
  }
#pragma unroll
  for (int m = 1; m < 64; m <<= 1) { s += __shfl_xor(s, m, 64); s2 += __shfl_xor(s2, m, 64); }
  const float mean = s * (1.f / 768.f);
  const float var = s2 * (1.f / 768.f) - mean * mean;
  const float rstd = rsqrtf(var + 1e-7f);
  const float4* gv = (const float4*)gw;
  const float4* bv = (const float4*)bw;
#pragma unroll
  for (int k = 0; k < 3; ++k) {
    int c = t + k * 64;
    float4 g = gv[c], bb = bv[c];
    float4 y = make_float4((v[k].x - mean) * rstd * g.x + bb.x,
                           (v[k].y - mean) * rstd * g.y + bb.y,
                           (v[k].z - mean) * rstd * g.z + bb.z,
                           (v[k].w - mean) * rstd * g.w + bb.w);
    ((float4*)(o32 + base))[c] = y;
    bf16x4 yb = {(bf16)y.x, (bf16)y.y, (bf16)y.z, (bf16)y.w};
    *(bf16x4*)(ob + base + c * 4) = yb;
  }
}

__global__ __launch_bounds__(64) void ln_emb_kernel(const float* __restrict__ x,
                                                    const float* __restrict__ pos,
                                                    const float* __restrict__ gw,
                                                    const float* __restrict__ bw,
                                                    const int* __restrict__ mask,
                                                    float* __restrict__ o32,
                                                    bf16* __restrict__ ob) {
  const int row = blockIdx.x, t = threadIdx.x;
  const int sp = row & 511;
  const size_t base = (size_t)row * 768;
  const float4* xv = (const float4*)(x + base);
  const float4* pv = (const float4*)(pos + (size_t)sp * 768);
  float4 v[3];
  float s = 0.f, s2 = 0.f;
#pragma unroll
  for (int k = 0; k < 3; ++k) {
    float4 a = xv[t + k * 64], b = pv[t + k * 64];
    v[k] = make_float4(a.x + b.x, a.y + b.y, a.z + b.z, a.w + b.w);
    s += v[k].x + v[k].y + v[k].z + v[k].w;
    s2 += v[k].x * v[k].x + v[k].y * v[k].y + v[k].z * v[k].z + v[k].w * v[k].w;
  }
#pragma unroll
  for (int m = 1; m < 64; m <<= 1) { s += __shfl_xor(s, m, 64); s2 += __shfl_xor(s2, m, 64); }
  const float mean = s * (1.f / 768.f);
  const float var = s2 * (1.f / 768.f) - mean * mean;
  const float rstd = rsqrtf(var + 1e-7f);
  const float mk = (float)mask[row];
  const float4* gv = (const float4*)gw;
  const float4* bv = (const float4*)bw;
#pragma unroll
  for (int k = 0; k < 3; ++k) {
    int c = t + k * 64;
    float4 g = gv[c], bb = bv[c];
    float4 y = make_float4(((v[k].x - mean) * rstd * g.x + bb.x) * mk,
                           ((v[k].y - mean) * rstd * g.y + bb.y) * mk,
                           ((v[k].z - mean) * rstd * g.z + bb.z) * mk,
                           ((v[k].w - mean) * rstd * g.w + bb.w) * mk);
    ((float4*)(o32 + base))[c] = y;
    bf16x4 yb = {(bf16)y.x, (bf16)y.y, (bf16)y.z, (bf16)y.w};
    *(bf16x4*)(ob + base + c * 4) = yb;
  }
}

// ---------------------------------------------------------------------------
// Fused disentangled attention v2.
// Grid (h, qt, b) -> h == blockIdx.x%8 pins each head to one XCD (L2 locality).
// 68 KB LDS -> 2 WG/CU.  Band terms scatter-written straight into score
// buffers S1/S2[li][lj] (each band MFMA output element maps to exactly one
// score cell: lj = q-dd+63 for c2p, li = dd+kj-63 for p2c), eliminating the
// G1s/G2s buffers and the gather phase.  All fragment-read strides padded
// (104/72) or XOR-swizzled (Vst) for 2-way-or-free bank access.
// ---------------------------------------------------------------------------
__global__ __launch_bounds__(256) void attn_kernel(const bf16* __restrict__ qkv,
                                                   const bf16* __restrict__ pkpq,
                                                   const int* __restrict__ mask,
                                                   bf16* __restrict__ ctx) {
  constexpr float INV_SCALE = 0.05892556509887897f;  // 1/sqrt(288)
  constexpr float NEG = -3.402823466e38f;
  const int h = blockIdx.x, qt = blockIdx.y, b = blockIdx.z;
  const int i0 = qt * 64;
  const int tid = threadIdx.x;
  const int wid = tid >> 6, lane = tid & 63;
  const int lr = lane & 15, lg = lane >> 4;
  const int w16 = wid * 16;

  __shared__ __align__(16) bf16 Qs[64 * 104];
  __shared__ __align__(16) bf16 Ks[64 * 104];
  __shared__ __align__(16) bf16 Pb[64 * 104];   // band staging; Ps (stride 72) overlays
  __shared__ __align__(16) bf16 Vst[96 * 64];   // V^T, chunk-XOR swizzled
  __shared__ __align__(16) bf16 S1[64 * 68];    // c2p score term
  __shared__ __align__(16) bf16 S2[64 * 68];    // p2c score term
  bf16* Ps = Pb;

  // stage Q once: 64 rows x 13 chunks (104-el padded rows), linear LDS fill
  for (int p = wid; p < 13; p += 4) {
    int ci = p * 64 + lane;
    int r = ci / 13, c = ci - r * 13;
    glds16(qkv + (size_t)(b * 512 + i0 + r) * 2304 + h * 96 + c * 8, (char*)Qs + p * 1024);
  }

  auto stagePb = [&](int colbase, int rowbase) {
    for (int p = wid; p < 13; p += 4) {
      int ci = p * 64 + lane;
      int r = ci / 13, c = ci - r * 13;
      int gr = rowbase + r; gr = gr > 1023 ? 1023 : gr;
      glds16(pkpq + (size_t)gr * 1536 + colbase + c * 8, (char*)Pb + p * 1024);
    }
  };

  // band MFMA + scatter into score buffer. afr = A-fragments (Q rows for G1,
  // K rows for G2). Output el: (rowout = w16+lg*4+rr, dd = dphase+dtl*16+lr).
  auto bandPhase = [&](const bf16x8* afr, int dphase, bf16* Sdst, bool isG1) {
#pragma unroll
    for (int dtl = 0; dtl < 4; ++dtl) {
      f32x4 g = f32x4{0.f, 0.f, 0.f, 0.f};
#pragma unroll
      for (int ks = 0; ks < 3; ++ks)
        g = mfma16(afr[ks], *(const bf16x8*)(&Pb[(dtl * 16 + lr) * 104 + ks * 32 + lg * 8]), g);
      const int dd = dphase + dtl * 16 + lr;
#pragma unroll
      for (int rr = 0; rr < 4; ++rr) {
        const int rowout = w16 + lg * 4 + rr;
        if (isG1) {
          int lj = rowout - dd + 63;
          if (lj >= 0 && lj < 64) Sdst[rowout * 68 + lj] = (bf16)g[rr];
        } else {
          int li = dd + rowout - 63;
          if (li >= 0 && li < 64) Sdst[li * 68 + rowout] = (bf16)g[rr];
        }
      }
    }
  };

  int qm[4];
#pragma unroll
  for (int r = 0; r < 4; ++r) qm[r] = mask[b * 512 + i0 + w16 + lg * 4 + r];

  f32x4 O[6];
#pragma unroll
  for (int dt = 0; dt < 6; ++dt) O[dt] = f32x4{0.f, 0.f, 0.f, 0.f};
  float mrun[4] = {NEG, NEG, NEG, NEG};
  float lrun[4] = {0.f, 0.f, 0.f, 0.f};
  bf16x8 qf[3];

  for (int jt = 0; jt < 8; ++jt) {
    const int j0 = jt * 64;
    const int d0 = i0 - j0 + 449;
    __syncthreads();  // B0: prev-jt PV/softmax reads of Ks/Vst/Ps/S1/S2 done
    // V global loads early (latency hides under staging+compute)
    bf16x8 vv[3];
    {
      const int j = lane, dcb = wid * 3;
#pragma unroll
      for (int q = 0; q < 3; ++q)
        vv[q] = *(const bf16x8*)(qkv + (size_t)(b * 512 + j0 + j) * 2304 + 1536 + h * 96 +
                                 (dcb + q) * 8);
    }
    // stage K tile
    for (int p = wid; p < 13; p += 4) {
      int ci = p * 64 + lane;
      int r = ci / 13, c = ci - r * 13;
      glds16(qkv + (size_t)(b * 512 + j0 + r) * 2304 + 768 + h * 96 + c * 8, (char*)Ks + p * 1024);
    }
    stagePb(h * 96, d0);  // PK rows d0..d0+63
    // V^T into swizzled LDS (waits only own vv regs)
    {
      const int j = lane, dcb = wid * 3;
#pragma unroll
      for (int q = 0; q < 3; ++q) {
        const int dbase = (dcb + q) * 8;
#pragma unroll
        for (int e = 0; e < 8; ++e) {
          const int d = dbase + e;
          Vst[d * 64 + ((((j >> 3) ^ (d & 7)) << 3) | (j & 7))] = vv[q][e];
        }
      }
    }
    __syncthreads();  // B1: Ks + PK-half0 staged (vmcnt drained)
    if (jt == 0) {
#pragma unroll
      for (int ks = 0; ks < 3; ++ks)
        qf[ks] = *(const bf16x8*)(&Qs[(w16 + lr) * 104 + ks * 32 + lg * 8]);
    }
    bf16x8 kf[3];
#pragma unroll
    for (int ks = 0; ks < 3; ++ks)
      kf[ks] = *(const bf16x8*)(&Ks[(w16 + lr) * 104 + ks * 32 + lg * 8]);

    bandPhase(qf, 0, S1, true);  // G1 half0 (dd 0..63)
    __syncthreads();             // B2: Pb reads done
    stagePb(h * 96, d0 + 64);    // PK rows d0+64..d0+127
    // QK^T overlaps the PK-half1 staging latency
    f32x4 sv[4];
#pragma unroll
    for (int n = 0; n < 4; ++n) sv[n] = f32x4{0.f, 0.f, 0.f, 0.f};
#pragma unroll
    for (int ks = 0; ks < 3; ++ks) {
#pragma unroll
      for (int n = 0; n < 4; ++n) {
        bf16x8 bb = *(const bf16x8*)(&Ks[(n * 16 + lr) * 104 + ks * 32 + lg * 8]);
        sv[n] = mfma16(qf[ks], bb, sv[n]);
      }
    }
    __syncthreads();             // B3
    bandPhase(qf, 64, S1, true); // G1 half1 (dd 64..127)
    __syncthreads();             // B4
    stagePb(768 + h * 96, d0);   // PQ rows d0..d0+63
    __syncthreads();             // B5
    bandPhase(kf, 0, S2, false); // G2 half0
    __syncthreads();             // B6
    stagePb(768 + h * 96, d0 + 64);
    __syncthreads();             // B7
    bandPhase(kf, 64, S2, false);
    __syncthreads();             // B8: S1,S2,Vst visible; Pb free -> Ps overlay

    int km[4];
#pragma unroll
    for (int n = 0; n < 4; ++n) km[n] = mask[b * 512 + j0 + n * 16 + lr];

    float pv[4][4];
#pragma unroll
    for (int n = 0; n < 4; ++n) {
      const int lj = n * 16 + lr;
#pragma unroll
      for (int r = 0; r < 4; ++r) {
        const int li = w16 + lg * 4 + r;
        const int off = li * 68 + lj;
        float t = (sv[n][r] + (float)S1[off] + (float)S2[off]) * INV_SCALE;
        pv[n][r] = (qm[r] != 0 && km[n] != 0) ? t : NEG;
      }
    }

    float alpha[4];
#pragma unroll
    for (int r = 0; r < 4; ++r) {
      float mx = fmaxf(fmaxf(pv[0][r], pv[1][r]), fmaxf(pv[2][r], pv[3][r]));
#pragma unroll
      for (int m = 1; m < 16; m <<= 1) mx = fmaxf(mx, __shfl_xor(mx, m, 64));
      float mn = fmaxf(mrun[r], mx);
      alpha[r] = __expf(mrun[r] - mn);
      mrun[r] = mn;
    }
#pragma unroll
    for (int n = 0; n < 4; ++n)
#pragma unroll
      for (int r = 0; r < 4; ++r) pv[n][r] = __expf(pv[n][r] - mrun[r]);
#pragma unroll
    for (int r = 0; r < 4; ++r) {
      float sm = pv[0][r] + pv[1][r] + pv[2][r] + pv[3][r];
#pragma unroll
      for (int m = 1; m < 16; m <<= 1) sm += __shfl_xor(sm, m, 64);
      lrun[r] = lrun[r] * alpha[r] + sm;
    }
    // Ps (stride 72, overlays Pb): wave writes its own 16 q-rows
#pragma unroll
    for (int n = 0; n < 4; ++n)
#pragma unroll
      for (int r = 0; r < 4; ++r)
        Ps[(w16 + lg * 4 + r) * 72 + n * 16 + lr] = (bf16)pv[n][r];
#pragma unroll
    for (int dt = 0; dt < 6; ++dt)
#pragma unroll
      for (int r = 0; r < 4; ++r) O[dt][r] *= alpha[r];
    // PV: A = own-wave Ps rows (per-wave in-order LDS, no barrier needed)
#pragma unroll
    for (int js = 0; js < 2; ++js) {
      bf16x8 pa = *(const bf16x8*)(&Ps[(w16 + lr) * 72 + js * 32 + lg * 8]);
#pragma unroll
      for (int dt = 0; dt < 6; ++dt) {
        bf16x8 bb = *(const bf16x8*)(&Vst[(dt * 16 + lr) * 64 + (((js * 4 + lg) ^ (lr & 7)) << 3)]);
        O[dt] = mfma16(pa, bb, O[dt]);
      }
    }
  }

  float inv[4];
#pragma unroll
  for (int r = 0; r < 4; ++r) inv[r] = 1.f / lrun[r];
#pragma unroll
  for (int dt = 0; dt < 6; ++dt)
#pragma unroll
    for (int r = 0; r < 4; ++r)
      ctx[(size_t)(b * 512 + i0 + w16 + lg * 4 + r) * 768 + h * 96 + dt * 16 + lr] =
          (bf16)(O[dt][r] * inv[r]);
}

// ---------------------------------------------------------------------------
// Host orchestration
// ---------------------------------------------------------------------------
extern "C" void kernel_launch(void* const* d_in, const int* in_sizes, int n_in, void* d_out,
                              int out_size, void* d_ws, size_t ws_size, hipStream_t stream) {
  const float* x    = (const float*)d_in[0];
  const float* pos  = (const float*)d_in[1];
  const float* rel  = (const float*)d_in[2];
  const float* lneg = (const float*)d_in[3];
  const float* lneb = (const float*)d_in[4];
  const float* Wq   = (const float*)d_in[5];
  const float* bq   = (const float*)d_in[6];
  const float* Wk   = (const float*)d_in[7];
  const float* bk   = (const float*)d_in[8];
  const float* Wv   = (const float*)d_in[9];
  const float* bv   = (const float*)d_in[10];
  const float* Wo   = (const float*)d_in[11];
  const float* bo   = (const float*)d_in[12];
  const float* Wpk  = (const float*)d_in[13];
  const float* bpk  = (const float*)d_in[14];
  const float* Wpq  = (const float*)d_in[15];
  const float* bpq  = (const float*)d_in[16];
  const float* ln1g = (const float*)d_in[17];
  const float* ln1b = (const float*)d_in[18];
  const float* Wi   = (const float*)d_in[19];
  const float* bi   = (const float*)d_in[20];
  const float* Wo2  = (const float*)d_in[21];
  const float* bo2  = (const float*)d_in[22];
  const float* ln2g = (const float*)d_in[23];
  const float* ln2b = (const float*)d_in[24];
  const int* mask   = (const int*)d_in[25];
  float* out = (float*)d_out;

  char* w = (char*)d_ws;
  auto alloc = [&](size_t bytes) { char* p = w; w += (bytes + 255) & ~(size_t)255; return p; };
  bf16* wqkvT = (bf16*)alloc((size_t)2304 * 768 * 2);
  bf16* woT   = (bf16*)alloc((size_t)768 * 768 * 2);
  bf16* wppT  = (bf16*)alloc((size_t)1536 * 768 * 2);
  bf16* wiT   = (bf16*)alloc((size_t)3072 * 768 * 2);
  bf16* wo2T  = (bf16*)alloc((size_t)768 * 3072 * 2);
  bf16* relb  = (bf16*)alloc((size_t)1024 * 768 * 2);
  float* h32  = (float*)alloc((size_t)4096 * 768 * 4);
  bf16* hb    = (bf16*)alloc((size_t)4096 * 768 * 2);
  bf16* qkvb  = (bf16*)alloc((size_t)4096 * 2304 * 2);
  bf16* ppb   = (bf16*)alloc((size_t)1024 * 1536 * 2);
  bf16* ctxb  = (bf16*)alloc((size_t)4096 * 768 * 2);
  float* t32  = (float*)alloc((size_t)4096 * 768 * 4);
  bf16* ffib  = (bf16*)alloc((size_t)4096 * 3072 * 2);
  float* bqkvF = (float*)alloc((size_t)6 * 2304 * 4);
  float* bppF  = (float*)alloc((size_t)6 * 1536 * 4);
  (void)ws_size; (void)in_sizes; (void)n_in; (void)out_size;

  ln_emb_kernel<<<4096, 64, 0, stream>>>(x, pos, lneg, lneb, mask, h32, hb);
  concat_qkv_bias<<<dim3(9, 6), 256, 0, stream>>>(bq, bk, bv, bqkvF);
  concat_pp_bias<<<dim3(6, 6), 256, 0, stream>>>(bpk, bpq, bppF);

  for (int l = 0; l < 6; ++l) {
    PrepArgs pa;
    int n = 0, total = 0;
    auto add = [&](const float* s, bf16* d, int Kd, int Nd, int tr) {
      pa.e[n].src = s; pa.e[n].dst = d; pa.e[n].K = Kd; pa.e[n].N = Nd;
      pa.e[n].tiles = (Kd / 32) * (Nd / 32); pa.e[n].trans = tr;
      total += pa.e[n].tiles; ++n;
    };
    add(Wq + (size_t)l * 768 * 768, wqkvT, 768, 768, 1);
    add(Wk + (size_t)l * 768 * 768, wqkvT + (size_t)768 * 768, 768, 768, 1);
    add(Wv + (size_t)l * 768 * 768, wqkvT + (size_t)1536 * 768, 768, 768, 1);
    add(Wo + (size_t)l * 768 * 768, woT, 768, 768, 1);
    add(Wpk + (size_t)l * 768 * 768, wppT, 768, 768, 1);
    add(Wpq + (size_t)l * 768 * 768, wppT + (size_t)768 * 768, 768, 768, 1);
    add(Wi + (size_t)l * 768 * 3072, wiT, 768, 3072, 1);
    add(Wo2 + (size_t)l * 3072 * 768, wo2T, 3072, 768, 1);
    if (l == 0) add(rel, relb, 1024, 768, 0);
    pa.n = n;
    prep_weights<<<total, 256, 0, stream>>>(pa);

    gemm_bt<128, 128, 0><<<dim3(2304 / 128, 4096 / 128), 256, 0, stream>>>(
        hb, wqkvT, bqkvF + l * 2304, qkvb, nullptr, 4096, 2304, 768);
    gemm_bt<128, 128, 0><<<dim3(1536 / 128, 1024 / 128), 256, 0, stream>>>(
        relb, wppT, bppF + l * 1536, ppb, nullptr, 1024, 1536, 768);
    attn_kernel<<<dim3(8, 8, 8), 256, 0, stream>>>(qkvb, ppb, mask, ctxb);
    gemm_bt<64, 128, 2><<<dim3(768 / 128, 4096 / 64), 256, 0, stream>>>(
        ctxb, woT, bo + (size_t)l * 768, nullptr, t32, 4096, 768, 768);
    ln_res_kernel<<<4096, 64, 0, stream>>>(t32, h32, ln1g + l * 768, ln1b + l * 768, h32, hb);
    gemm_bt<128, 128, 1><<<dim3(3072 / 128, 4096 / 128), 256, 0, stream>>>(
        hb, wiT, bi + (size_t)l * 3072, ffib, nullptr, 4096, 3072, 768);
    gemm_bt<64, 128, 2><<<dim3(768 / 128, 4096 / 64), 256, 0, stream>>>(
        ffib, wo2T, bo2 + (size_t)l * 768, nullptr, t32, 4096, 768, 3072);
    float* oo = (l == 5) ? out : h32;
    ln_res_kernel<<<4096, 64, 0, stream>>>(t32, h32, ln2g + l * 768, ln2b + l * 768, oo, hb);
  }
}